// Round 1
// baseline (181147.766 us; speedup 1.0000x reference)
//
#include <hip/hip_runtime.h>
#include <hip/hip_cooperative_groups.h>

namespace cg = cooperative_groups;

#define B_   256
#define S_   1024
#define H_   512
#define G4_  2048
#define T_   256
#define BT_  32      // batch tile per block  (8 batch groups)
#define KT_  16      // hidden tile per block (32 k groups)
#define NBLK 256
#define NTHR 256

// ---------------------------------------------------------------------------
// Precompute fused decoder weights: W2[j][k] = dec_Whh[j][k] + dec_Wih[j]*lin_W[k]
// (folds the scalar output-feedback x_t = h_t·lin_W + lin_b into the gate matmul,
//  removing the second grid sync per decoder step)
// ---------------------------------------------------------------------------
__global__ void fuse_dec_weights(const float* __restrict__ dec_Whh,
                                 const float* __restrict__ dec_Wih,
                                 const float* __restrict__ lin_W,
                                 float* __restrict__ W2)
{
    int idx = blockIdx.x * NTHR + threadIdx.x;   // 2048*512 elements
    int j = idx >> 9;
    int k = idx & 511;
    W2[idx] = fmaf(dec_Wih[j], lin_W[k], dec_Whh[idx]);
}

__device__ __forceinline__ float sigmoidf_(float x) {
    return 1.0f / (1.0f + expf(-x));
}

// Stage this block's 32x512 h tile global->LDS, XOR-swizzled on float4 columns
// so inner-loop reads (8 lanes at stride 512 floats) are bank-conflict-free.
__device__ __forceinline__ void stage_tile(float* __restrict__ hs,
                                           const float* __restrict__ src)
{
    const float4* s4 = (const float4*)src;
    float4* d4 = (float4*)hs;
    #pragma unroll
    for (int i = 0; i < 16; ++i) {
        int idx = (int)threadIdx.x + (i << 8);   // 4096 float4s
        float4 v = s4[idx];
        int row = idx >> 7;       // /128 float4s per row
        int c4  = idx & 127;
        d4[(row << 7) | (c4 ^ (row & 7))] = v;
    }
}

// 8 dot products (4 gates x 2 hidden idx) of length 512 against the LDS h row.
__device__ __forceinline__ void dot8_(const float* __restrict__ W, int k0,
                                      const float* __restrict__ hsrow, int swz,
                                      float acc[8])
{
    const float4* __restrict__ hp = (const float4*)hsrow;
    const float4* __restrict__ wp[8];
    #pragma unroll
    for (int g = 0; g < 4; ++g)
        #pragma unroll
        for (int j = 0; j < 2; ++j)
            wp[g * 2 + j] = (const float4*)(W + (size_t)((g << 9) + k0 + j) * H_);

    #pragma unroll 2
    for (int q = 0; q < H_ / 4; ++q) {
        float4 hv = hp[q ^ swz];
        #pragma unroll
        for (int r = 0; r < 8; ++r) {
            float4 wv = wp[r][q];
            acc[r] = fmaf(hv.x, wv.x, acc[r]);
            acc[r] = fmaf(hv.y, wv.y, acc[r]);
            acc[r] = fmaf(hv.z, wv.z, acc[r]);
            acc[r] = fmaf(hv.w, wv.w, acc[r]);
        }
    }
}

// out[b][tcol] = h·lin_W + lin_b, using the already-staged LDS tile.
__device__ __forceinline__ void write_out(const float* __restrict__ hs,
                                          const float* __restrict__ lin_W,
                                          float lb, float* __restrict__ out,
                                          int b, int tcol, int tb, int tk, int swz)
{
    const float* hr = hs + tb * H_;
    float s = 0.f;
    #pragma unroll
    for (int i = 0; i < 64; ++i) {
        int k = (tk << 6) + i;
        int addr = ((((k >> 2) ^ swz) << 2) | (k & 3));
        s = fmaf(hr[addr], lin_W[k], s);
    }
    s += __shfl_down(s, 4, 8);
    s += __shfl_down(s, 2, 8);
    s += __shfl_down(s, 1, 8);
    if (tk == 0) out[b * T_ + tcol] = s + lb;
}

// ---------------------------------------------------------------------------
// Persistent cooperative kernel: whole encoder + decoder in one launch.
// Block owns state tile (32 batches x 16 hidden): c stays in registers forever,
// h ping-pongs through global with ONE grid.sync per step.
// ---------------------------------------------------------------------------
__global__ void __launch_bounds__(NTHR, 1)
seq2seq_kernel(const float* __restrict__ inputs,
               const float* __restrict__ enc_Wih,
               const float* __restrict__ enc_Whh,
               const float* __restrict__ enc_bih,
               const float* __restrict__ enc_bhh,
               const float* __restrict__ dec_Wih,
               const float* __restrict__ dec_Whh,
               const float* __restrict__ dec_bih,
               const float* __restrict__ dec_bhh,
               const float* __restrict__ lin_W,
               const float* __restrict__ lin_b,
               const float* __restrict__ W2,
               float* __restrict__ hbuf,       // 2 * B_*H_ floats, ping-pong
               float* __restrict__ out)        // B_ * T_
{
    cg::grid_group grid = cg::this_grid();
    __shared__ float hs[BT_ * H_];             // 64 KiB, XOR-swizzled

    const int tid = threadIdx.x;
    const int tk  = tid & 7;                   // 8 k-subgroups
    const int tb  = tid >> 3;                  // 32 local batches
    const int kg  = blockIdx.x & 31;           // 32 k groups
    const int bg  = blockIdx.x >> 5;           // 8 batch groups
    const int b   = bg * BT_ + tb;             // global batch
    const int k0  = kg * KT_ + (tk << 1);      // 2 consecutive hidden idx
    const int swz = tb & 7;

    float* hA = hbuf;
    float* hB = hbuf + B_ * H_;

    // zero-init h (ws is poisoned each launch); c lives in registers
    *(float2*)&hA[b * H_ + k0] = make_float2(0.f, 0.f);
    float c2[2] = {0.f, 0.f};

    // per-row encoder constants (rows: g*512 + k0 + j, gate order i,f,g,o)
    float encB[8], encWihR[8];
    #pragma unroll
    for (int g = 0; g < 4; ++g)
        #pragma unroll
        for (int j = 0; j < 2; ++j) {
            int row = (g << 9) + k0 + j;
            encB[g * 2 + j]   = enc_bih[row] + enc_bhh[row];
            encWihR[g * 2 + j] = enc_Wih[row];
        }

    float* hcur = hA;
    float* hnxt = hB;
    const float* hsrow = hs + tb * H_;

    // ---------------- encoder: 1024 steps ----------------
    for (int t = 0; t < S_; ++t) {
        grid.sync();
        stage_tile(hs, hcur + bg * BT_ * H_);
        __syncthreads();

        float xv = inputs[b * S_ + t];
        float acc[8];
        #pragma unroll
        for (int r = 0; r < 8; ++r) acc[r] = fmaf(xv, encWihR[r], encB[r]);
        dot8_(enc_Whh, k0, hsrow, swz, acc);

        float h2[2];
        #pragma unroll
        for (int j = 0; j < 2; ++j) {
            float ig = sigmoidf_(acc[0 + j]);
            float fg = sigmoidf_(acc[2 + j]);
            float gg = tanhf(acc[4 + j]);
            float og = sigmoidf_(acc[6 + j]);
            float cn = fmaf(fg, c2[j], ig * gg);
            c2[j] = cn;
            h2[j] = og * tanhf(cn);
        }
        *(float2*)&hnxt[b * H_ + k0] = make_float2(h2[0], h2[1]);
        float* tmp = hcur; hcur = hnxt; hnxt = tmp;
    }

    // ---------------- decoder constants ----------------
    float decB0[8], decBF[8], decWihR[8];
    float lb = lin_b[0];
    #pragma unroll
    for (int g = 0; g < 4; ++g)
        #pragma unroll
        for (int j = 0; j < 2; ++j) {
            int row = (g << 9) + k0 + j;
            float b0  = dec_bih[row] + dec_bhh[row];
            float wih = dec_Wih[row];
            decB0[g * 2 + j]  = b0;
            decWihR[g * 2 + j] = wih;
            decBF[g * 2 + j]  = fmaf(wih, lb, b0);   // bias + Wih*lin_b (fused x)
        }

    // ---------------- decoder: 256 steps ----------------
    // iteration t: reads h_t, computes h_{t+1}; out_{t-1} = h_t·lin_W (kg==0 blocks)
    for (int t = 0; t < T_; ++t) {
        grid.sync();
        stage_tile(hs, hcur + bg * BT_ * H_);
        __syncthreads();

        if (kg == 0 && t > 0)
            write_out(hs, lin_W, lb, out, b, t - 1, tb, tk, swz);

        float acc[8];
        if (t == 0) {
            // x0 = inputs[:, S-1, 0] with un-fused weights
            float xv = inputs[b * S_ + (S_ - 1)];
            #pragma unroll
            for (int r = 0; r < 8; ++r) acc[r] = fmaf(xv, decWihR[r], decB0[r]);
            dot8_(dec_Whh, k0, hsrow, swz, acc);
        } else {
            // x_t folded into W2
            #pragma unroll
            for (int r = 0; r < 8; ++r) acc[r] = decBF[r];
            dot8_(W2, k0, hsrow, swz, acc);
        }

        float h2[2];
        #pragma unroll
        for (int j = 0; j < 2; ++j) {
            float ig = sigmoidf_(acc[0 + j]);
            float fg = sigmoidf_(acc[2 + j]);
            float gg = tanhf(acc[4 + j]);
            float og = sigmoidf_(acc[6 + j]);
            float cn = fmaf(fg, c2[j], ig * gg);
            c2[j] = cn;
            h2[j] = og * tanhf(cn);
        }
        *(float2*)&hnxt[b * H_ + k0] = make_float2(h2[0], h2[1]);
        float* tmp = hcur; hcur = hnxt; hnxt = tmp;
    }

    // ---------------- epilogue: out_{T-1} from h_T ----------------
    grid.sync();
    if (kg == 0) {
        stage_tile(hs, hcur + bg * BT_ * H_);
        __syncthreads();
        write_out(hs, lin_W, lb, out, b, T_ - 1, tb, tk, swz);
    }
}

// ---------------------------------------------------------------------------
extern "C" void kernel_launch(void* const* d_in, const int* in_sizes, int n_in,
                              void* d_out, int out_size, void* d_ws, size_t ws_size,
                              hipStream_t stream)
{
    (void)in_sizes; (void)n_in; (void)out_size; (void)ws_size;

    const float* inputs  = (const float*)d_in[0];
    const float* enc_Wih = (const float*)d_in[1];
    const float* enc_Whh = (const float*)d_in[2];
    const float* enc_bih = (const float*)d_in[3];
    const float* enc_bhh = (const float*)d_in[4];
    const float* dec_Wih = (const float*)d_in[5];
    const float* dec_Whh = (const float*)d_in[6];
    const float* dec_bih = (const float*)d_in[7];
    const float* dec_bhh = (const float*)d_in[8];
    const float* lin_W   = (const float*)d_in[9];
    const float* lin_b   = (const float*)d_in[10];
    float* out = (float*)d_out;

    // workspace layout: W2 (2048*512 f32 = 4 MB) | hbuf (2*256*512 f32 = 1 MB)
    float* W2   = (float*)d_ws;
    float* hbuf = W2 + (size_t)G4_ * H_;

    hipLaunchKernelGGL(fuse_dec_weights, dim3((G4_ * H_) / NTHR), dim3(NTHR), 0, stream,
                       dec_Whh, dec_Wih, lin_W, W2);

    void* args[] = {
        (void*)&inputs, (void*)&enc_Wih, (void*)&enc_Whh, (void*)&enc_bih, (void*)&enc_bhh,
        (void*)&dec_Wih, (void*)&dec_Whh, (void*)&dec_bih, (void*)&dec_bhh,
        (void*)&lin_W, (void*)&lin_b, (void*)&W2, (void*)&hbuf, (void*)&out
    };
    hipLaunchCooperativeKernel((void*)seq2seq_kernel, dim3(NBLK), dim3(NTHR),
                               args, 0, stream);
}

// Round 2
// 45234.769 us; speedup vs baseline: 4.0046x; 4.0046x over previous
//
#include <hip/hip_runtime.h>

#define B_    256
#define S_    1024
#define H_    512
#define G4_   2048
#define T_    256
#define NBLK  256
#define NTHR  256

typedef const __attribute__((address_space(1))) void gas_void;
typedef __attribute__((address_space(3))) void       las_void;

// ---------------------------------------------------------------------------
// W2[j][k] = dec_Whh[j][k] + dec_Wih[j]*lin_W[k]  (folds scalar feedback)
// ---------------------------------------------------------------------------
__global__ void fuse_dec_weights(const float* __restrict__ dec_Whh,
                                 const float* __restrict__ dec_Wih,
                                 const float* __restrict__ lin_W,
                                 float* __restrict__ W2)
{
    int idx = blockIdx.x * NTHR + threadIdx.x;
    int j = idx >> 9, k = idx & 511;
    W2[idx] = fmaf(dec_Wih[j], lin_W[k], dec_Whh[idx]);
}

__device__ __forceinline__ float sigmoidf_(float x) { return 1.0f / (1.0f + expf(-x)); }

// ---------------------------------------------------------------------------
// Per-batch-group barrier: 32 blocks, parity counters, device-scope atomics.
// bar[0..1] = arrival counters (parity), bar[2..3] = release generations.
// ---------------------------------------------------------------------------
__device__ __forceinline__ void bg_barrier(unsigned* bar, int ph)
{
    __syncthreads();
    if (threadIdx.x == 0) {
        const int p = ph & 1;
        const unsigned target = (unsigned)(ph >> 1) + 1u;
        __threadfence();                       // release h-writes (wb L2)
        unsigned prev = __hip_atomic_fetch_add(&bar[p], 1u, __ATOMIC_ACQ_REL,
                                               __HIP_MEMORY_SCOPE_AGENT);
        if (prev == 31u) {
            __hip_atomic_store(&bar[p], 0u, __ATOMIC_RELAXED, __HIP_MEMORY_SCOPE_AGENT);
            __hip_atomic_fetch_add(&bar[2 + p], 1u, __ATOMIC_ACQ_REL,
                                   __HIP_MEMORY_SCOPE_AGENT);
        } else {
            while (__hip_atomic_load(&bar[2 + p], __ATOMIC_RELAXED,
                                     __HIP_MEMORY_SCOPE_AGENT) < target)
                __builtin_amdgcn_s_sleep(2);
            __threadfence();                   // acquire (invalidate stale caches)
        }
    }
    __syncthreads();
}

// Stage 16 rows (16 x 512 f32 = 32 KB) global -> LDS, async 16B direct-to-LDS.
__device__ __forceinline__ void stage16(float* __restrict__ hs,
                                        const float* __restrict__ src,
                                        int w, int lane)
{
    #pragma unroll
    for (int it = 0; it < 8; ++it) {
        const int ubase = it * 1024 + w * 256;          // floats, wave-uniform
        __builtin_amdgcn_global_load_lds(
            (gas_void*)(src + ubase + lane * 4),
            (las_void*)(hs + ubase),
            16, 0, 0);
    }
}

// Load one weight row's 64 k-elements (interleaved chunks kgrp+8q) into regs.
__device__ __forceinline__ void loadw(const float* __restrict__ W, int j,
                                      int kgrp, float4* wreg)
{
    const float* base = W + (size_t)j * H_ + 4 * kgrp;
    #pragma unroll
    for (int q = 0; q < 16; ++q)
        wreg[q] = *(const float4*)(base + 32 * q);
}

// 16 batch rows x 2 gate rows of h.W^T partials; k-reduce over 8 lanes; -> gbuf
__device__ __forceinline__ void dots16(const float* __restrict__ hs,
                                       float (*__restrict__ gbw)[17],
                                       const float4* __restrict__ w0,
                                       const float4* __restrict__ w1,
                                       int jgrp, int kgrp)
{
    #pragma unroll 2
    for (int b16 = 0; b16 < 16; ++b16) {
        const float4* hr = (const float4*)(hs + b16 * H_) + kgrp;
        float4 a0 = make_float4(0.f, 0.f, 0.f, 0.f);
        float4 a1 = make_float4(0.f, 0.f, 0.f, 0.f);
        #pragma unroll
        for (int q = 0; q < 16; ++q) {
            float4 hv = hr[8 * q];               // chunk kgrp+8q: conflict-free
            a0.x = fmaf(hv.x, w0[q].x, a0.x); a0.y = fmaf(hv.y, w0[q].y, a0.y);
            a0.z = fmaf(hv.z, w0[q].z, a0.z); a0.w = fmaf(hv.w, w0[q].w, a0.w);
            a1.x = fmaf(hv.x, w1[q].x, a1.x); a1.y = fmaf(hv.y, w1[q].y, a1.y);
            a1.z = fmaf(hv.z, w1[q].z, a1.z); a1.w = fmaf(hv.w, w1[q].w, a1.w);
        }
        float s0 = (a0.x + a0.y) + (a0.z + a0.w);
        float s1 = (a1.x + a1.y) + (a1.z + a1.w);
        s0 += __shfl_down(s0, 4, 8); s0 += __shfl_down(s0, 2, 8); s0 += __shfl_down(s0, 1, 8);
        s1 += __shfl_down(s1, 4, 8); s1 += __shfl_down(s1, 2, 8); s1 += __shfl_down(s1, 1, 8);
        if (kgrp == 0) { gbw[jgrp * 2][b16] = s0; gbw[jgrp * 2 + 1][b16] = s1; }
    }
}

// h[b].lin_W partial dot; valid on lanes (tid&15)==0 after return.
__device__ __forceinline__ float outdot(const float* __restrict__ hs,
                                        const float* __restrict__ lin_W, int tid)
{
    const int b16 = tid >> 4, kc = tid & 15;
    const float* hr = hs + b16 * H_;
    float s = 0.f;
    #pragma unroll
    for (int q = 0; q < 8; ++q) {
        const int off = 4 * kc + 64 * q;
        float4 hv = *(const float4*)(hr + off);
        float4 wv = *(const float4*)(lin_W + off);
        s = fmaf(hv.x, wv.x, s); s = fmaf(hv.y, wv.y, s);
        s = fmaf(hv.z, wv.z, s); s = fmaf(hv.w, wv.w, s);
    }
    s += __shfl_down(s, 8, 16); s += __shfl_down(s, 4, 16);
    s += __shfl_down(s, 2, 16); s += __shfl_down(s, 1, 16);
    return s;
}

// ---------------------------------------------------------------------------
// Persistent kernel. Weights live in VGPRs (128 regs/thread), c in 2 regs/lane,
// h ping-pongs via global with one per-batch-group barrier per step.
// ---------------------------------------------------------------------------
__global__ void __launch_bounds__(NTHR, 1)
seq2seq_kernel(const float* __restrict__ inputs,
               const float* __restrict__ enc_Wih,
               const float* __restrict__ enc_Whh,
               const float* __restrict__ enc_bih,
               const float* __restrict__ enc_bhh,
               const float* __restrict__ dec_Wih,
               const float* __restrict__ dec_bih,
               const float* __restrict__ dec_bhh,
               const float* __restrict__ lin_W,
               const float* __restrict__ lin_b,
               const float* __restrict__ W2,
               float* __restrict__ hA0,
               float* __restrict__ hB0,
               float* __restrict__ xcor,
               unsigned* __restrict__ bars,
               float* __restrict__ out)
{
    __shared__ float hs[16 * H_];            // 32 KiB: one 16-batch half of h
    __shared__ float gbuf[4][16][17];        // per-wave gate sums, +1 pad

    const int tid  = threadIdx.x;
    const int w    = tid >> 6;
    const int lane = tid & 63;
    const int jgrp = lane >> 3;
    const int kgrp = lane & 7;
    const int bg   = blockIdx.x >> 5;        // 8 batch groups x 32 blocks
    const int lb   = blockIdx.x & 31;
    const int bgbase = bg * 32;

    unsigned* bar = bars + bg * 64;          // 256B-padded per-bg record

    // gate-row ownership: r = hsub*4 + gate; thread holds r0,r1 = jgrp*2(+1)
    const int r0 = jgrp * 2, r1 = r0 + 1;
    const int hbase = lb * 16 + w * 4;
    const int j0 = (r0 & 3) * H_ + hbase + (r0 >> 2);
    const int j1 = (r1 & 3) * H_ + hbase + (r1 >> 2);

    float4 w0[16], w1[16];                   // 128 VGPRs of weights
    loadw(enc_Whh, j0, kgrp, w0);
    loadw(enc_Whh, j1, kgrp, w1);

    // nonlinearity-pass lane mapping: one (hidden,batch) pair per lane
    const int hsubN = lane >> 4, bN = lane & 15;
    const int hidN  = lb * 16 + w * 4 + hsubN;

    const float ewi = enc_Wih[hidN],          ewf = enc_Wih[H_ + hidN];
    const float ewg = enc_Wih[2 * H_ + hidN], ewo = enc_Wih[3 * H_ + hidN];
    const float ebi = enc_bih[hidN] + enc_bhh[hidN];
    const float ebf = enc_bih[H_ + hidN] + enc_bhh[H_ + hidN];
    const float ebg = enc_bih[2 * H_ + hidN] + enc_bhh[2 * H_ + hidN];
    const float ebo = enc_bih[3 * H_ + hidN] + enc_bhh[3 * H_ + hidN];
    const float linb = lin_b[0];

    // zero this bg's slice of hA (h_0 = 0); visibility via barrier 0
    *(float2*)(hA0 + (size_t)blockIdx.x * 512 + tid * 2) = make_float2(0.f, 0.f);

    float cc0 = 0.f, cc1 = 0.f;              // cell state, 1 (hid,b) per lane/half
    float* hA = hA0;
    float* hB = hB0;
    int ph = 0;

    // ---------------- encoder: 1024 steps ----------------
    #pragma unroll 1
    for (int t = 0; t < S_; ++t) {
        bg_barrier(bar, ph++);
        stage16(hs, hA + (size_t)bgbase * H_, w, lane);
        __syncthreads();
        dots16(hs, gbuf[w], w0, w1, jgrp, kgrp);
        __syncthreads();
        stage16(hs, hA + (size_t)(bgbase + 16) * H_, w, lane);   // overlap half1
        {   // nonlinearity, half 0
            float gi = gbuf[w][hsubN * 4 + 0][bN], gf = gbuf[w][hsubN * 4 + 1][bN];
            float gg = gbuf[w][hsubN * 4 + 2][bN], go = gbuf[w][hsubN * 4 + 3][bN];
            float xv = inputs[(size_t)(bgbase + bN) * S_ + t];
            gi = fmaf(xv, ewi, gi + ebi); gf = fmaf(xv, ewf, gf + ebf);
            gg = fmaf(xv, ewg, gg + ebg); go = fmaf(xv, ewo, go + ebo);
            float i_ = sigmoidf_(gi), f_ = sigmoidf_(gf);
            float g_ = tanhf(gg),     o_ = sigmoidf_(go);
            float cn = fmaf(f_, cc0, i_ * g_);
            cc0 = cn;
            hB[(size_t)(bgbase + bN) * H_ + hidN] = o_ * tanhf(cn);
        }
        __syncthreads();
        dots16(hs, gbuf[w], w0, w1, jgrp, kgrp);
        {   // nonlinearity, half 1
            float gi = gbuf[w][hsubN * 4 + 0][bN], gf = gbuf[w][hsubN * 4 + 1][bN];
            float gg = gbuf[w][hsubN * 4 + 2][bN], go = gbuf[w][hsubN * 4 + 3][bN];
            float xv = inputs[(size_t)(bgbase + 16 + bN) * S_ + t];
            gi = fmaf(xv, ewi, gi + ebi); gf = fmaf(xv, ewf, gf + ebf);
            gg = fmaf(xv, ewg, gg + ebg); go = fmaf(xv, ewo, go + ebo);
            float i_ = sigmoidf_(gi), f_ = sigmoidf_(gf);
            float g_ = tanhf(gg),     o_ = sigmoidf_(go);
            float cn = fmaf(f_, cc1, i_ * g_);
            cc1 = cn;
            hB[(size_t)(bgbase + 16 + bN) * H_ + hidN] = o_ * tanhf(cn);
        }
        float* tmp = hA; hA = hB; hB = tmp;
    }

    // ---------------- xcor + weight swap phase ----------------
    bg_barrier(bar, ph++);
    if (lb == 0) {   // xcor[b] = x0[b] - (h_enc.lin_W + lin_b)
        stage16(hs, hA + (size_t)bgbase * H_, w, lane);
        __syncthreads();
        {
            float s = outdot(hs, lin_W, tid);
            if ((tid & 15) == 0) {
                int b = bgbase + (tid >> 4);
                xcor[b] = inputs[(size_t)b * S_ + (S_ - 1)] - (s + linb);
            }
        }
        __syncthreads();
        stage16(hs, hA + (size_t)(bgbase + 16) * H_, w, lane);
        __syncthreads();
        {
            float s = outdot(hs, lin_W, tid);
            if ((tid & 15) == 0) {
                int b = bgbase + 16 + (tid >> 4);
                xcor[b] = inputs[(size_t)b * S_ + (S_ - 1)] - (s + linb);
            }
        }
    }
    loadw(W2, j0, kgrp, w0);                 // swap weights to fused decoder W2
    loadw(W2, j1, kgrp, w1);
    const float dwi = dec_Wih[hidN],          dwf = dec_Wih[H_ + hidN];
    const float dwg = dec_Wih[2 * H_ + hidN], dwo = dec_Wih[3 * H_ + hidN];
    const float dbi = dec_bih[hidN] + dec_bhh[hidN] + dwi * linb;
    const float dbf = dec_bih[H_ + hidN] + dec_bhh[H_ + hidN] + dwf * linb;
    const float dbg = dec_bih[2 * H_ + hidN] + dec_bhh[2 * H_ + hidN] + dwg * linb;
    const float dbo = dec_bih[3 * H_ + hidN] + dec_bhh[3 * H_ + hidN] + dwo * linb;

    // ---------------- decoder: 256 steps ----------------
    #pragma unroll 1
    for (int t = 0; t < T_; ++t) {
        bg_barrier(bar, ph++);
        stage16(hs, hA + (size_t)bgbase * H_, w, lane);
        __syncthreads();
        dots16(hs, gbuf[w], w0, w1, jgrp, kgrp);
        if (lb == 0 && t > 0) {
            float s = outdot(hs, lin_W, tid);
            if ((tid & 15) == 0)
                out[(size_t)(bgbase + (tid >> 4)) * T_ + (t - 1)] = s + linb;
        }
        __syncthreads();
        stage16(hs, hA + (size_t)(bgbase + 16) * H_, w, lane);
        {   // nonlinearity, half 0
            float gi = gbuf[w][hsubN * 4 + 0][bN] + dbi;
            float gf = gbuf[w][hsubN * 4 + 1][bN] + dbf;
            float gg = gbuf[w][hsubN * 4 + 2][bN] + dbg;
            float go = gbuf[w][hsubN * 4 + 3][bN] + dbo;
            if (t == 0) {
                float xc = xcor[bgbase + bN];
                gi = fmaf(xc, dwi, gi); gf = fmaf(xc, dwf, gf);
                gg = fmaf(xc, dwg, gg); go = fmaf(xc, dwo, go);
            }
            float i_ = sigmoidf_(gi), f_ = sigmoidf_(gf);
            float g_ = tanhf(gg),     o_ = sigmoidf_(go);
            float cn = fmaf(f_, cc0, i_ * g_);
            cc0 = cn;
            hB[(size_t)(bgbase + bN) * H_ + hidN] = o_ * tanhf(cn);
        }
        __syncthreads();
        dots16(hs, gbuf[w], w0, w1, jgrp, kgrp);
        if (lb == 0 && t > 0) {
            float s = outdot(hs, lin_W, tid);
            if ((tid & 15) == 0)
                out[(size_t)(bgbase + 16 + (tid >> 4)) * T_ + (t - 1)] = s + linb;
        }
        {   // nonlinearity, half 1
            float gi = gbuf[w][hsubN * 4 + 0][bN] + dbi;
            float gf = gbuf[w][hsubN * 4 + 1][bN] + dbf;
            float gg = gbuf[w][hsubN * 4 + 2][bN] + dbg;
            float go = gbuf[w][hsubN * 4 + 3][bN] + dbo;
            if (t == 0) {
                float xc = xcor[bgbase + 16 + bN];
                gi = fmaf(xc, dwi, gi); gf = fmaf(xc, dwf, gf);
                gg = fmaf(xc, dwg, gg); go = fmaf(xc, dwo, go);
            }
            float i_ = sigmoidf_(gi), f_ = sigmoidf_(gf);
            float g_ = tanhf(gg),     o_ = sigmoidf_(go);
            float cn = fmaf(f_, cc1, i_ * g_);
            cc1 = cn;
            hB[(size_t)(bgbase + 16 + bN) * H_ + hidN] = o_ * tanhf(cn);
        }
        float* tmp = hA; hA = hB; hB = tmp;
    }

    // ---------------- epilogue: out[:,255] from h_d256 ----------------
    bg_barrier(bar, ph++);
    if (lb == 0) {
        stage16(hs, hA + (size_t)bgbase * H_, w, lane);
        __syncthreads();
        {
            float s = outdot(hs, lin_W, tid);
            if ((tid & 15) == 0)
                out[(size_t)(bgbase + (tid >> 4)) * T_ + (T_ - 1)] = s + linb;
        }
        __syncthreads();
        stage16(hs, hA + (size_t)(bgbase + 16) * H_, w, lane);
        __syncthreads();
        {
            float s = outdot(hs, lin_W, tid);
            if ((tid & 15) == 0)
                out[(size_t)(bgbase + 16 + (tid >> 4)) * T_ + (T_ - 1)] = s + linb;
        }
    }
}

// ---------------------------------------------------------------------------
extern "C" void kernel_launch(void* const* d_in, const int* in_sizes, int n_in,
                              void* d_out, int out_size, void* d_ws, size_t ws_size,
                              hipStream_t stream)
{
    (void)in_sizes; (void)n_in; (void)out_size; (void)ws_size;

    const float* inputs  = (const float*)d_in[0];
    const float* enc_Wih = (const float*)d_in[1];
    const float* enc_Whh = (const float*)d_in[2];
    const float* enc_bih = (const float*)d_in[3];
    const float* enc_bhh = (const float*)d_in[4];
    const float* dec_Wih = (const float*)d_in[5];
    const float* dec_Whh = (const float*)d_in[6];
    const float* dec_bih = (const float*)d_in[7];
    const float* dec_bhh = (const float*)d_in[8];
    const float* lin_W   = (const float*)d_in[9];
    const float* lin_b   = (const float*)d_in[10];
    float* out = (float*)d_out;

    // ws layout: W2 (4MB) | hA (512KB) | hB (512KB) | xcor (1KB) | barriers (2KB)
    float* W2   = (float*)d_ws;
    float* hA   = W2 + (size_t)G4_ * H_;
    float* hB   = hA + (size_t)B_ * H_;
    float* xcor = hB + (size_t)B_ * H_;
    unsigned* bars = (unsigned*)(xcor + B_);

    hipMemsetAsync((void*)bars, 0, 8 * 64 * sizeof(unsigned), stream);

    hipLaunchKernelGGL(fuse_dec_weights, dim3((G4_ * H_) / NTHR), dim3(NTHR), 0, stream,
                       dec_Whh, dec_Wih, lin_W, W2);

    void* args[] = {
        (void*)&inputs, (void*)&enc_Wih, (void*)&enc_Whh, (void*)&enc_bih, (void*)&enc_bhh,
        (void*)&dec_Wih, (void*)&dec_bih, (void*)&dec_bhh,
        (void*)&lin_W, (void*)&lin_b, (void*)&W2,
        (void*)&hA, (void*)&hB, (void*)&xcor, (void*)&bars, (void*)&out
    };
    hipLaunchCooperativeKernel((void*)seq2seq_kernel, dim3(NBLK), dim3(NTHR),
                               args, 0, stream);
}

// Round 3
// 16066.103 us; speedup vs baseline: 11.2752x; 2.8155x over previous
//
#include <hip/hip_runtime.h>

#define B_    256
#define S_    1024
#define H_    512
#define G4_   2048
#define T_    256
#define NBLK  256
#define NTHR  1024
#define BB    16          // batches per batch-group
#define NBG   16          // batch groups
#define LBN   16          // blocks per batch-group

// ---------------------------------------------------------------------------
// W2[j][k] = dec_Whh[j][k] + dec_Wih[j]*lin_W[k]  (folds scalar x-feedback)
// ---------------------------------------------------------------------------
__global__ void fuse_dec_weights(const float* __restrict__ dec_Whh,
                                 const float* __restrict__ dec_Wih,
                                 const float* __restrict__ lin_W,
                                 float* __restrict__ W2)
{
    int idx = blockIdx.x * 256 + threadIdx.x;
    int j = idx >> 9, k = idx & 511;
    W2[idx] = fmaf(dec_Wih[j], lin_W[k], dec_Whh[idx]);
}

__device__ __forceinline__ float sigmoidf_(float x) { return 1.0f / (1.0f + expf(-x)); }

// ---------------------------------------------------------------------------
// Per-bg barrier: ONE monotonic agent-scope counter, no reset, no fences.
// All shared data (h, xcor) moves via relaxed agent atomics (sc1 -> MALL),
// so no cache maintenance is needed; __syncthreads drains stores (vmcnt 0).
// ---------------------------------------------------------------------------
__device__ __forceinline__ void bg_barrier(unsigned* arr, int ph)
{
    __syncthreads();
    if (threadIdx.x == 0) {
        unsigned prev = __hip_atomic_fetch_add(arr, 1u, __ATOMIC_RELAXED,
                                               __HIP_MEMORY_SCOPE_AGENT);
        const unsigned target = (unsigned)(ph + 1) * LBN;
        if (prev != target - 1u) {
            while (__hip_atomic_load(arr, __ATOMIC_RELAXED,
                                     __HIP_MEMORY_SCOPE_AGENT) < target)
                __builtin_amdgcn_s_sleep(1);
        }
    }
    __syncthreads();
}

// ---------------------------------------------------------------------------
// Persistent kernel: 256 blocks x 1024 threads (16 waves, 4/SIMD).
// Block owns 32 hidden x 4 gates (128 rows) for one 16-batch group.
// Weights in VGPRs (16 float4/thread), c in 1 reg/thread, h via L3 atomics.
// ---------------------------------------------------------------------------
__global__ void __launch_bounds__(NTHR)
seq2seq_kernel(const float* __restrict__ inputs,
               const float* __restrict__ enc_Wih,
               const float* __restrict__ enc_Whh,
               const float* __restrict__ enc_bih,
               const float* __restrict__ enc_bhh,
               const float* __restrict__ dec_Wih,
               const float* __restrict__ dec_bih,
               const float* __restrict__ dec_bhh,
               const float* __restrict__ lin_W,
               const float* __restrict__ lin_b,
               const float* __restrict__ W2,
               float* __restrict__ hA0,
               float* __restrict__ hB0,
               float* __restrict__ xcor,
               unsigned* __restrict__ bars,
               float* __restrict__ out)
{
    __shared__ float hs[BB * H_];            // 32 KiB: the bg's 16-batch h
    __shared__ float gbuf[128][BB + 1];      // gate sums, padded

    const int tid  = threadIdx.x;
    const int w    = tid >> 6;               // wave 0..15
    const int lane = tid & 63;
    const int jgrp = (tid >> 4) & 3;         // row-pair group
    const int kgrp = tid & 15;               // k slice
    const int bg   = blockIdx.x & (NBG - 1); // XCD-friendly interleave
    const int lb   = blockIdx.x >> 4;        // 0..15: hidden-slice owner
    const int bgbase = bg * BB;

    unsigned* arr = bars + bg * 64;          // 256B-padded per-bg counter

    // two gate rows per thread: local rows r0, r1; r = gate*32 + hsub
    const int r0 = w * 8 + jgrp * 2, r1 = r0 + 1;
    const int j0 = (r0 >> 5) * H_ + lb * 32 + (r0 & 31);
    const int j1 = (r1 >> 5) * H_ + lb * 32 + (r1 & 31);

    float4 w0[8], w1[8];                     // 64 VGPRs of weights
    auto loadw = [&](const float* __restrict__ W) {
        const float4* p0 = (const float4*)(W + (size_t)j0 * H_) + kgrp;
        const float4* p1 = (const float4*)(W + (size_t)j1 * H_) + kgrp;
        #pragma unroll
        for (int q = 0; q < 8; ++q) { w0[q] = p0[16 * q]; w1[q] = p1[16 * q]; }
    };

    // stage bg's h (32 KB) global->LDS via agent-scope (sc1/L3) 8B loads
    auto stage = [&](float* hsrc) {
        unsigned long long* s = (unsigned long long*)hsrc;
        unsigned long long* d = (unsigned long long*)hs;
        unsigned long long t0 = __hip_atomic_load(s + tid,        __ATOMIC_RELAXED, __HIP_MEMORY_SCOPE_AGENT);
        unsigned long long t1 = __hip_atomic_load(s + 1024 + tid, __ATOMIC_RELAXED, __HIP_MEMORY_SCOPE_AGENT);
        unsigned long long t2 = __hip_atomic_load(s + 2048 + tid, __ATOMIC_RELAXED, __HIP_MEMORY_SCOPE_AGENT);
        unsigned long long t3 = __hip_atomic_load(s + 3072 + tid, __ATOMIC_RELAXED, __HIP_MEMORY_SCOPE_AGENT);
        d[tid] = t0; d[1024 + tid] = t1; d[2048 + tid] = t2; d[3072 + tid] = t3;
    };

    // 16 batches x 2 rows of h.W^T; k-reduce over 16 lanes; results -> gbuf
    auto dots = [&]() {
        #pragma unroll 2
        for (int b = 0; b < BB; ++b) {
            const float4* hr = (const float4*)(hs + b * H_) + kgrp;
            float4 a0 = make_float4(0.f, 0.f, 0.f, 0.f);
            float4 a1 = make_float4(0.f, 0.f, 0.f, 0.f);
            #pragma unroll
            for (int q = 0; q < 8; ++q) {
                float4 hv = hr[16 * q];
                a0.x = fmaf(hv.x, w0[q].x, a0.x); a0.y = fmaf(hv.y, w0[q].y, a0.y);
                a0.z = fmaf(hv.z, w0[q].z, a0.z); a0.w = fmaf(hv.w, w0[q].w, a0.w);
                a1.x = fmaf(hv.x, w1[q].x, a1.x); a1.y = fmaf(hv.y, w1[q].y, a1.y);
                a1.z = fmaf(hv.z, w1[q].z, a1.z); a1.w = fmaf(hv.w, w1[q].w, a1.w);
            }
            float s0 = (a0.x + a0.y) + (a0.z + a0.w);
            float s1 = (a1.x + a1.y) + (a1.z + a1.w);
            s0 += __shfl_down(s0, 8, 16); s0 += __shfl_down(s0, 4, 16);
            s0 += __shfl_down(s0, 2, 16); s0 += __shfl_down(s0, 1, 16);
            s1 += __shfl_down(s1, 8, 16); s1 += __shfl_down(s1, 4, 16);
            s1 += __shfl_down(s1, 2, 16); s1 += __shfl_down(s1, 1, 16);
            if (kgrp == 0) { gbuf[r0][b] = s0; gbuf[r1][b] = s1; }
        }
    };

    // h[b]·lin_W for b = wave index; result on lane 0 of each wave
    auto proj = [&]() -> float {
        const int kc = tid & 63;
        const float* hr = hs + w * H_;
        float4 h0 = *(const float4*)(hr + 4 * kc);
        float4 h1 = *(const float4*)(hr + 256 + 4 * kc);
        float4 v0 = *(const float4*)(lin_W + 4 * kc);
        float4 v1 = *(const float4*)(lin_W + 256 + 4 * kc);
        float s = h0.x * v0.x + h0.y * v0.y + h0.z * v0.z + h0.w * v0.w;
        s = fmaf(h1.x, v1.x, s); s = fmaf(h1.y, v1.y, s);
        s = fmaf(h1.z, v1.z, s); s = fmaf(h1.w, v1.w, s);
        s += __shfl_down(s, 32); s += __shfl_down(s, 16); s += __shfl_down(s, 8);
        s += __shfl_down(s, 4);  s += __shfl_down(s, 2);  s += __shfl_down(s, 1);
        return s;
    };

    // nonlinearity-state mapping: threads 0..511 own one (hidden,batch) pair
    const int hsubN = tid & 31, bN = tid >> 5;       // bN valid for tid<512
    const int hidN  = lb * 32 + hsubN;
    const bool stateful = (tid < 512);

    const float ewi = enc_Wih[hidN],          ewf = enc_Wih[H_ + hidN];
    const float ewg = enc_Wih[2 * H_ + hidN], ewo = enc_Wih[3 * H_ + hidN];
    const float ebi = enc_bih[hidN] + enc_bhh[hidN];
    const float ebf = enc_bih[H_ + hidN] + enc_bhh[H_ + hidN];
    const float ebg = enc_bih[2 * H_ + hidN] + enc_bhh[2 * H_ + hidN];
    const float ebo = enc_bih[3 * H_ + hidN] + enc_bhh[3 * H_ + hidN];
    const float linb = lin_b[0];

    loadw(enc_Whh);

    // h_0 = 0 (ws is poisoned each launch); visible after barrier 0
    if (stateful)
        __hip_atomic_store(&hA0[(size_t)(bgbase + bN) * H_ + hidN], 0.f,
                           __ATOMIC_RELAXED, __HIP_MEMORY_SCOPE_AGENT);

    float cc = 0.f;
    float* hcur = hA0;
    float* hnxt = hB0;
    int ph = 0;

    // ---------------- encoder: 1024 steps ----------------
    #pragma unroll 1
    for (int t = 0; t < S_; ++t) {
        bg_barrier(arr, ph++);
        stage(hcur + (size_t)bgbase * H_);
        __syncthreads();
        dots();
        __syncthreads();
        if (stateful) {
            float xv = inputs[(size_t)(bgbase + bN) * S_ + t];
            float gi = gbuf[hsubN][bN]      + fmaf(xv, ewi, ebi);
            float gf = gbuf[32 + hsubN][bN] + fmaf(xv, ewf, ebf);
            float gg = gbuf[64 + hsubN][bN] + fmaf(xv, ewg, ebg);
            float go = gbuf[96 + hsubN][bN] + fmaf(xv, ewo, ebo);
            float i_ = sigmoidf_(gi), f_ = sigmoidf_(gf);
            float g_ = tanhf(gg),     o_ = sigmoidf_(go);
            float cn = fmaf(f_, cc, i_ * g_);
            cc = cn;
            __hip_atomic_store(&hnxt[(size_t)(bgbase + bN) * H_ + hidN],
                               o_ * tanhf(cn),
                               __ATOMIC_RELAXED, __HIP_MEMORY_SCOPE_AGENT);
        }
        float* tt = hcur; hcur = hnxt; hnxt = tt;
    }

    // ---------------- xcor phase + decoder weight/bias swap ----------------
    bg_barrier(arr, ph++);
    if (lb == 0) {          // xcor[b] = x0_true - (h_enc·lin_W + lin_b)
        stage(hcur + (size_t)bgbase * H_);
        __syncthreads();
        float s = proj();
        if ((tid & 63) == 0) {
            float x0 = inputs[(size_t)(bgbase + w) * S_ + (S_ - 1)];
            __hip_atomic_store(&xcor[bgbase + w], x0 - (s + linb),
                               __ATOMIC_RELAXED, __HIP_MEMORY_SCOPE_AGENT);
        }
    }
    loadw(W2);
    const float dwi = dec_Wih[hidN],          dwf = dec_Wih[H_ + hidN];
    const float dwg = dec_Wih[2 * H_ + hidN], dwo = dec_Wih[3 * H_ + hidN];
    const float dbi = dec_bih[hidN] + dec_bhh[hidN] + dwi * linb;
    const float dbf = dec_bih[H_ + hidN] + dec_bhh[H_ + hidN] + dwf * linb;
    const float dbg = dec_bih[2 * H_ + hidN] + dec_bhh[2 * H_ + hidN] + dwg * linb;
    const float dbo = dec_bih[3 * H_ + hidN] + dec_bhh[3 * H_ + hidN] + dwo * linb;

    // ---------------- decoder: 256 steps ----------------
    #pragma unroll 1
    for (int t = 0; t < T_; ++t) {
        bg_barrier(arr, ph++);
        stage(hcur + (size_t)bgbase * H_);
        __syncthreads();
        dots();
        if (lb == 0 && t > 0) {       // out[:, t-1] = h_t·lin_W + lin_b
            float s = proj();
            if ((tid & 63) == 0)
                out[(size_t)(bgbase + w) * T_ + (t - 1)] = s + linb;
        }
        __syncthreads();
        if (stateful) {
            float gi = gbuf[hsubN][bN]      + dbi;
            float gf = gbuf[32 + hsubN][bN] + dbf;
            float gg = gbuf[64 + hsubN][bN] + dbg;
            float go = gbuf[96 + hsubN][bN] + dbo;
            if (t == 0) {
                float xc = __hip_atomic_load(&xcor[bgbase + bN],
                                             __ATOMIC_RELAXED, __HIP_MEMORY_SCOPE_AGENT);
                gi = fmaf(xc, dwi, gi); gf = fmaf(xc, dwf, gf);
                gg = fmaf(xc, dwg, gg); go = fmaf(xc, dwo, go);
            }
            float i_ = sigmoidf_(gi), f_ = sigmoidf_(gf);
            float g_ = tanhf(gg),     o_ = sigmoidf_(go);
            float cn = fmaf(f_, cc, i_ * g_);
            cc = cn;
            __hip_atomic_store(&hnxt[(size_t)(bgbase + bN) * H_ + hidN],
                               o_ * tanhf(cn),
                               __ATOMIC_RELAXED, __HIP_MEMORY_SCOPE_AGENT);
        }
        float* tt = hcur; hcur = hnxt; hnxt = tt;
    }

    // ---------------- epilogue: out[:, T-1] from h_dec_256 ----------------
    bg_barrier(arr, ph++);
    if (lb == 0) {
        stage(hcur + (size_t)bgbase * H_);
        __syncthreads();
        float s = proj();
        if ((tid & 63) == 0)
            out[(size_t)(bgbase + w) * T_ + (T_ - 1)] = s + linb;
    }
}

// ---------------------------------------------------------------------------
extern "C" void kernel_launch(void* const* d_in, const int* in_sizes, int n_in,
                              void* d_out, int out_size, void* d_ws, size_t ws_size,
                              hipStream_t stream)
{
    (void)in_sizes; (void)n_in; (void)out_size; (void)ws_size;

    const float* inputs  = (const float*)d_in[0];
    const float* enc_Wih = (const float*)d_in[1];
    const float* enc_Whh = (const float*)d_in[2];
    const float* enc_bih = (const float*)d_in[3];
    const float* enc_bhh = (const float*)d_in[4];
    const float* dec_Wih = (const float*)d_in[5];
    const float* dec_Whh = (const float*)d_in[6];
    const float* dec_bih = (const float*)d_in[7];
    const float* dec_bhh = (const float*)d_in[8];
    const float* lin_W   = (const float*)d_in[9];
    const float* lin_b   = (const float*)d_in[10];
    float* out = (float*)d_out;

    // ws: W2 (4MB) | hA (512KB) | hB (512KB) | xcor (1KB) | barriers (4KB)
    float* W2   = (float*)d_ws;
    float* hA   = W2 + (size_t)G4_ * H_;
    float* hB   = hA + (size_t)B_ * H_;
    float* xcor = hB + (size_t)B_ * H_;
    unsigned* bars = (unsigned*)(xcor + B_);

    hipMemsetAsync((void*)bars, 0, NBG * 64 * sizeof(unsigned), stream);

    hipLaunchKernelGGL(fuse_dec_weights, dim3((G4_ * H_) / 256), dim3(256), 0, stream,
                       dec_Whh, dec_Wih, lin_W, W2);

    void* args[] = {
        (void*)&inputs, (void*)&enc_Wih, (void*)&enc_Whh, (void*)&enc_bih, (void*)&enc_bhh,
        (void*)&dec_Wih, (void*)&dec_bih, (void*)&dec_bhh,
        (void*)&lin_W, (void*)&lin_b, (void*)&W2,
        (void*)&hA, (void*)&hB, (void*)&xcor, (void*)&bars, (void*)&out
    };
    hipLaunchCooperativeKernel((void*)seq2seq_kernel, dim3(NBLK), dim3(NTHR),
                               args, 0, stream);
}

// Round 5
// 11833.200 us; speedup vs baseline: 15.3084x; 1.3577x over previous
//
#include <hip/hip_runtime.h>

#define B_    256
#define S_    1024
#define H_    512
#define G4_   2048
#define T_    256
#define NBLK  256
#define NTHR  1024
#define BB    16          // batches per batch-group
#define NBG   16          // batch groups
#define LBN   16          // blocks per batch-group

// ---------------------------------------------------------------------------
// W2[j][k] = dec_Whh[j][k] + dec_Wih[j]*lin_W[k]  (folds scalar x-feedback)
// ---------------------------------------------------------------------------
__global__ void fuse_dec_weights(const float* __restrict__ dec_Whh,
                                 const float* __restrict__ dec_Wih,
                                 const float* __restrict__ lin_W,
                                 float* __restrict__ W2)
{
    int idx = blockIdx.x * 256 + threadIdx.x;
    int j = idx >> 9, k = idx & 511;
    W2[idx] = fmaf(dec_Wih[j], lin_W[k], dec_Whh[idx]);
}

__device__ __forceinline__ float sigmoidf_(float x) { return 1.0f / (1.0f + expf(-x)); }

// Sum over each 16-lane group via DPP row_shr (VALU pipe, NOT the DS pipe
// that __shfl/bpermute uses). Result valid in lane 15 of each 16-lane group.
// old=0 + bound_ctrl=true: invalid source lanes contribute 0 under either
// bound_ctrl convention.
__device__ __forceinline__ float row16_reduce(float v)
{
    float s = v;
    s += __int_as_float(__builtin_amdgcn_update_dpp(
            0, __float_as_int(s), 0x111, 0xf, 0xf, true));   // row_shr:1
    s += __int_as_float(__builtin_amdgcn_update_dpp(
            0, __float_as_int(s), 0x112, 0xf, 0xf, true));   // row_shr:2
    s += __int_as_float(__builtin_amdgcn_update_dpp(
            0, __float_as_int(s), 0x114, 0xf, 0xf, true));   // row_shr:4
    s += __int_as_float(__builtin_amdgcn_update_dpp(
            0, __float_as_int(s), 0x118, 0xf, 0xf, true));   // row_shr:8
    return s;
}

// ---------------------------------------------------------------------------
// Per-bg barrier: ONE monotonic agent-scope counter (sc1/MALL), no fences.
// Validated in R3 (absmax 6e-5): __syncthreads drains stores; relaxed atomics.
// ---------------------------------------------------------------------------
__device__ __forceinline__ void bg_barrier(unsigned* arr, int ph)
{
    __syncthreads();
    if (threadIdx.x == 0) {
        unsigned prev = __hip_atomic_fetch_add(arr, 1u, __ATOMIC_RELAXED,
                                               __HIP_MEMORY_SCOPE_AGENT);
        const unsigned target = (unsigned)(ph + 1) * LBN;
        if (prev != target - 1u) {
            while (__hip_atomic_load(arr, __ATOMIC_RELAXED,
                                     __HIP_MEMORY_SCOPE_AGENT) < target)
                __builtin_amdgcn_s_sleep(1);
        }
    }
    __syncthreads();
}

// ---------------------------------------------------------------------------
// Persistent kernel: 256 blocks x 1024 threads (16 waves, 4/SIMD).
// Block owns 32 hidden x 4 gates (128 rows) for one 16-batch group.
// Weights in VGPRs (16 float4/thread), c in 1 reg/thread, h via L3 atomics.
// ---------------------------------------------------------------------------
__global__ void __launch_bounds__(NTHR)
seq2seq_kernel(const float* __restrict__ inputs,
               const float* __restrict__ enc_Wih,
               const float* __restrict__ enc_Whh,
               const float* __restrict__ enc_bih,
               const float* __restrict__ enc_bhh,
               const float* __restrict__ dec_Wih,
               const float* __restrict__ dec_bih,
               const float* __restrict__ dec_bhh,
               const float* __restrict__ lin_W,
               const float* __restrict__ lin_b,
               const float* __restrict__ W2,
               float* __restrict__ hA0,
               float* __restrict__ hB0,
               float* __restrict__ xcor,
               unsigned* __restrict__ bars,
               float* __restrict__ out)
{
    __shared__ float hs[BB * H_];            // 32 KiB: the bg's 16-batch h
    __shared__ float gbuf[128][BB + 1];      // gate sums, padded

    const int tid  = threadIdx.x;
    const int w    = tid >> 6;               // wave 0..15
    const int lane = tid & 63;
    const int jgrp = (tid >> 4) & 3;         // row-pair group
    const int kgrp = tid & 15;               // k slice
    const int bg   = blockIdx.x & (NBG - 1); // XCD-friendly interleave
    const int lb   = blockIdx.x >> 4;        // 0..15: hidden-slice owner
    const int bgbase = bg * BB;

    unsigned* arr = bars + bg * 64;          // 256B-padded per-bg counter

    // two gate rows per thread: local rows r0, r1; r = gate*32 + hsub
    const int r0 = w * 8 + jgrp * 2, r1 = r0 + 1;
    const int j0 = (r0 >> 5) * H_ + lb * 32 + (r0 & 31);
    const int j1 = (r1 >> 5) * H_ + lb * 32 + (r1 & 31);

    float4 w0[8], w1[8];                     // 64 VGPRs of weights
    auto loadw = [&](const float* __restrict__ W) {
        const float4* p0 = (const float4*)(W + (size_t)j0 * H_) + kgrp;
        const float4* p1 = (const float4*)(W + (size_t)j1 * H_) + kgrp;
        #pragma unroll
        for (int q = 0; q < 8; ++q) { w0[q] = p0[16 * q]; w1[q] = p1[16 * q]; }
    };

    // stage bg's h (32 KB) global->LDS via agent-scope (sc1/L3) 8B loads
    auto stage = [&](float* hsrc) {
        unsigned long long* s = (unsigned long long*)hsrc;
        unsigned long long* d = (unsigned long long*)hs;
        unsigned long long t0 = __hip_atomic_load(s + tid,        __ATOMIC_RELAXED, __HIP_MEMORY_SCOPE_AGENT);
        unsigned long long t1 = __hip_atomic_load(s + 1024 + tid, __ATOMIC_RELAXED, __HIP_MEMORY_SCOPE_AGENT);
        unsigned long long t2 = __hip_atomic_load(s + 2048 + tid, __ATOMIC_RELAXED, __HIP_MEMORY_SCOPE_AGENT);
        unsigned long long t3 = __hip_atomic_load(s + 3072 + tid, __ATOMIC_RELAXED, __HIP_MEMORY_SCOPE_AGENT);
        d[tid] = t0; d[1024 + tid] = t1; d[2048 + tid] = t2; d[3072 + tid] = t3;
    };

    // 16 batches x 2 rows of h.W^T; k-reduce over 16 lanes via DPP; -> gbuf
    auto dots = [&]() {
        #pragma unroll 2
        for (int b = 0; b < BB; ++b) {
            const float4* hr = (const float4*)(hs + b * H_) + kgrp;
            float4 a0 = make_float4(0.f, 0.f, 0.f, 0.f);
            float4 a1 = make_float4(0.f, 0.f, 0.f, 0.f);
            #pragma unroll
            for (int q = 0; q < 8; ++q) {
                float4 hv = hr[16 * q];
                a0.x = fmaf(hv.x, w0[q].x, a0.x); a0.y = fmaf(hv.y, w0[q].y, a0.y);
                a0.z = fmaf(hv.z, w0[q].z, a0.z); a0.w = fmaf(hv.w, w0[q].w, a0.w);
                a1.x = fmaf(hv.x, w1[q].x, a1.x); a1.y = fmaf(hv.y, w1[q].y, a1.y);
                a1.z = fmaf(hv.z, w1[q].z, a1.z); a1.w = fmaf(hv.w, w1[q].w, a1.w);
            }
            float s0 = (a0.x + a0.y) + (a0.z + a0.w);
            float s1 = (a1.x + a1.y) + (a1.z + a1.w);
            s0 = row16_reduce(s0);
            s1 = row16_reduce(s1);
            if (kgrp == 15) { gbuf[r0][b] = s0; gbuf[r1][b] = s1; }
        }
    };

    // h[b]·lin_W for b = wave index; result on lane 0 of the wave
    auto proj = [&]() -> float {
        const int kc = tid & 63;
        const float* hr = hs + w * H_;
        float4 h0 = *(const float4*)(hr + 4 * kc);
        float4 h1 = *(const float4*)(hr + 256 + 4 * kc);
        float4 v0 = *(const float4*)(lin_W + 4 * kc);
        float4 v1 = *(const float4*)(lin_W + 256 + 4 * kc);
        float s = h0.x * v0.x + h0.y * v0.y + h0.z * v0.z + h0.w * v0.w;
        s = fmaf(h1.x, v1.x, s); s = fmaf(h1.y, v1.y, s);
        s = fmaf(h1.z, v1.z, s); s = fmaf(h1.w, v1.w, s);
        s += __shfl_down(s, 32); s += __shfl_down(s, 16); s += __shfl_down(s, 8);
        s += __shfl_down(s, 4);  s += __shfl_down(s, 2);  s += __shfl_down(s, 1);
        return s;
    };

    // nonlinearity-state mapping: threads 0..511 own one (hidden,batch) pair
    const int hsubN = tid & 31, bN = tid >> 5;       // bN valid for tid<512
    const int hidN  = lb * 32 + hsubN;
    const bool stateful = (tid < 512);

    const float ewi = enc_Wih[hidN],          ewf = enc_Wih[H_ + hidN];
    const float ewg = enc_Wih[2 * H_ + hidN], ewo = enc_Wih[3 * H_ + hidN];
    const float ebi = enc_bih[hidN] + enc_bhh[hidN];
    const float ebf = enc_bih[H_ + hidN] + enc_bhh[H_ + hidN];
    const float ebg = enc_bih[2 * H_ + hidN] + enc_bhh[2 * H_ + hidN];
    const float ebo = enc_bih[3 * H_ + hidN] + enc_bhh[3 * H_ + hidN];
    const float linb = lin_b[0];

    loadw(enc_Whh);

    // h_0 = 0 (ws is poisoned each launch); visible after barrier 0
    if (stateful)
        __hip_atomic_store(&hA0[(size_t)(bgbase + bN) * H_ + hidN], 0.f,
                           __ATOMIC_RELAXED, __HIP_MEMORY_SCOPE_AGENT);

    float cc = 0.f;
    float* hcur = hA0;
    float* hnxt = hB0;
    int ph = 0;

    // ---------------- encoder: 1024 steps ----------------
    #pragma unroll 1
    for (int t = 0; t < S_; ++t) {
        bg_barrier(arr, ph++);
        stage(hcur + (size_t)bgbase * H_);
        __syncthreads();
        dots();
        __syncthreads();
        if (stateful) {
            float xv = inputs[(size_t)(bgbase + bN) * S_ + t];
            float gi = gbuf[hsubN][bN]      + fmaf(xv, ewi, ebi);
            float gf = gbuf[32 + hsubN][bN] + fmaf(xv, ewf, ebf);
            float gg = gbuf[64 + hsubN][bN] + fmaf(xv, ewg, ebg);
            float go = gbuf[96 + hsubN][bN] + fmaf(xv, ewo, ebo);
            float i_ = sigmoidf_(gi), f_ = sigmoidf_(gf);
            float g_ = tanhf(gg),     o_ = sigmoidf_(go);
            float cn = fmaf(f_, cc, i_ * g_);
            cc = cn;
            __hip_atomic_store(&hnxt[(size_t)(bgbase + bN) * H_ + hidN],
                               o_ * tanhf(cn),
                               __ATOMIC_RELAXED, __HIP_MEMORY_SCOPE_AGENT);
        }
        float* tt = hcur; hcur = hnxt; hnxt = tt;
    }

    // ---------------- xcor phase + decoder weight/bias swap ----------------
    bg_barrier(arr, ph++);
    if (lb == 0) {          // xcor[b] = x0_true - (h_enc·lin_W + lin_b)
        stage(hcur + (size_t)bgbase * H_);
        __syncthreads();
        float s = proj();
        if ((tid & 63) == 0) {
            float x0 = inputs[(size_t)(bgbase + w) * S_ + (S_ - 1)];
            __hip_atomic_store(&xcor[bgbase + w], x0 - (s + linb),
                               __ATOMIC_RELAXED, __HIP_MEMORY_SCOPE_AGENT);
        }
    }
    loadw(W2);
    const float dwi = dec_Wih[hidN],          dwf = dec_Wih[H_ + hidN];
    const float dwg = dec_Wih[2 * H_ + hidN], dwo = dec_Wih[3 * H_ + hidN];
    const float dbi = dec_bih[hidN] + dec_bhh[hidN] + dwi * linb;
    const float dbf = dec_bih[H_ + hidN] + dec_bhh[H_ + hidN] + dwf * linb;
    const float dbg = dec_bih[2 * H_ + hidN] + dec_bhh[2 * H_ + hidN] + dwg * linb;
    const float dbo = dec_bih[3 * H_ + hidN] + dec_bhh[3 * H_ + hidN] + dwo * linb;

    // ---------------- decoder: 256 steps ----------------
    #pragma unroll 1
    for (int t = 0; t < T_; ++t) {
        bg_barrier(arr, ph++);
        stage(hcur + (size_t)bgbase * H_);
        __syncthreads();
        dots();
        if (lb == 0 && t > 0) {       // out[:, t-1] = h_t·lin_W + lin_b
            float s = proj();
            if ((tid & 63) == 0)
                out[(size_t)(bgbase + w) * T_ + (t - 1)] = s + linb;
        }
        __syncthreads();
        if (stateful) {
            float gi = gbuf[hsubN][bN]      + dbi;
            float gf = gbuf[32 + hsubN][bN] + dbf;
            float gg = gbuf[64 + hsubN][bN] + dbg;
            float go = gbuf[96 + hsubN][bN] + dbo;
            if (t == 0) {
                float xc = __hip_atomic_load(&xcor[bgbase + bN],
                                             __ATOMIC_RELAXED, __HIP_MEMORY_SCOPE_AGENT);
                gi = fmaf(xc, dwi, gi); gf = fmaf(xc, dwf, gf);
                gg = fmaf(xc, dwg, gg); go = fmaf(xc, dwo, go);
            }
            float i_ = sigmoidf_(gi), f_ = sigmoidf_(gf);
            float g_ = tanhf(gg),     o_ = sigmoidf_(go);
            float cn = fmaf(f_, cc, i_ * g_);
            cc = cn;
            __hip_atomic_store(&hnxt[(size_t)(bgbase + bN) * H_ + hidN],
                               o_ * tanhf(cn),
                               __ATOMIC_RELAXED, __HIP_MEMORY_SCOPE_AGENT);
        }
        float* tt = hcur; hcur = hnxt; hnxt = tt;
    }

    // ---------------- epilogue: out[:, T-1] from h_dec_256 ----------------
    bg_barrier(arr, ph++);
    if (lb == 0) {
        stage(hcur + (size_t)bgbase * H_);
        __syncthreads();
        float s = proj();
        if ((tid & 63) == 0)
            out[(size_t)(bgbase + w) * T_ + (T_ - 1)] = s + linb;
    }
}

// ---------------------------------------------------------------------------
extern "C" void kernel_launch(void* const* d_in, const int* in_sizes, int n_in,
                              void* d_out, int out_size, void* d_ws, size_t ws_size,
                              hipStream_t stream)
{
    (void)in_sizes; (void)n_in; (void)out_size; (void)ws_size;

    const float* inputs  = (const float*)d_in[0];
    const float* enc_Wih = (const float*)d_in[1];
    const float* enc_Whh = (const float*)d_in[2];
    const float* enc_bih = (const float*)d_in[3];
    const float* enc_bhh = (const float*)d_in[4];
    const float* dec_Wih = (const float*)d_in[5];
    const float* dec_Whh = (const float*)d_in[6];
    const float* dec_bih = (const float*)d_in[7];
    const float* dec_bhh = (const float*)d_in[8];
    const float* lin_W   = (const float*)d_in[9];
    const float* lin_b   = (const float*)d_in[10];
    float* out = (float*)d_out;

    // ws: W2 (4MB) | hA (512KB) | hB (512KB) | xcor (1KB) | barriers (4KB)
    float* W2   = (float*)d_ws;
    float* hA   = W2 + (size_t)G4_ * H_;
    float* hB   = hA + (size_t)B_ * H_;
    float* xcor = hB + (size_t)B_ * H_;
    unsigned* bars = (unsigned*)(xcor + B_);

    hipMemsetAsync((void*)bars, 0, NBG * 64 * sizeof(unsigned), stream);

    hipLaunchKernelGGL(fuse_dec_weights, dim3((G4_ * H_) / 256), dim3(256), 0, stream,
                       dec_Whh, dec_Wih, lin_W, W2);

    void* args[] = {
        (void*)&inputs, (void*)&enc_Wih, (void*)&enc_Whh, (void*)&enc_bih, (void*)&enc_bhh,
        (void*)&dec_Wih, (void*)&dec_bih, (void*)&dec_bhh,
        (void*)&lin_W, (void*)&lin_b, (void*)&W2,
        (void*)&hA, (void*)&hB, (void*)&xcor, (void*)&bars, (void*)&out
    };
    hipLaunchCooperativeKernel((void*)seq2seq_kernel, dim3(NBLK), dim3(NTHR),
                               args, 0, stream);
}

// Round 6
// 4510.987 us; speedup vs baseline: 40.1570x; 2.6232x over previous
//
#include <hip/hip_runtime.h>

#define B_    256
#define S_    1024
#define H_    512
#define G4_   2048
#define T_    256
#define NBLK  256
#define NTHR  1024
#define BB    16          // batches per batch-group
#define NBG   16          // batch groups
#define LBN   16          // blocks per batch-group
#define HSW   516         // LDS h row stride in words (512+4: bank-conflict pad)

typedef short bf8v  __attribute__((ext_vector_type(8)));   // 8 bf16 = 4 VGPR
typedef float f4v   __attribute__((ext_vector_type(4)));
typedef int   i32x4 __attribute__((ext_vector_type(4)));

#define PERM_HI 0x07060302u   // [s1.hi16 -> low short, s0.hi16 -> high short]
#define PERM_LO 0x05040100u   // [s1.lo16 -> low short, s0.lo16 -> high short]

// ---------------------------------------------------------------------------
// W2[j][k] = dec_Whh[j][k] + dec_Wih[j]*lin_W[k]  (folds scalar x-feedback)
// ---------------------------------------------------------------------------
__global__ void fuse_dec_weights(const float* __restrict__ dec_Whh,
                                 const float* __restrict__ dec_Wih,
                                 const float* __restrict__ lin_W,
                                 float* __restrict__ W2)
{
    int idx = blockIdx.x * 256 + threadIdx.x;
    int j = idx >> 9, k = idx & 511;
    W2[idx] = fmaf(dec_Wih[j], lin_W[k], dec_Whh[idx]);
}

__device__ __forceinline__ float sigmoidf_(float x) { return 1.0f / (1.0f + expf(-x)); }

// ---------------------------------------------------------------------------
// Per-bg barrier: ONE monotonic agent-scope counter (sc1/MALL), no fences.
// Validated R3/R5 (absmax 6e-5).
// ---------------------------------------------------------------------------
__device__ __forceinline__ void bg_barrier(unsigned* arr, int ph)
{
    __syncthreads();
    if (threadIdx.x == 0) {
        unsigned prev = __hip_atomic_fetch_add(arr, 1u, __ATOMIC_RELAXED,
                                               __HIP_MEMORY_SCOPE_AGENT);
        const unsigned target = (unsigned)(ph + 1) * LBN;
        if (prev != target - 1u) {
            while (__hip_atomic_load(arr, __ATOMIC_RELAXED,
                                     __HIP_MEMORY_SCOPE_AGENT) < target)
                __builtin_amdgcn_s_sleep(1);
        }
    }
    __syncthreads();
}

// ---------------------------------------------------------------------------
// Persistent kernel. h lives in global as packed [hi16|lo16] bf16-split words
// (exact once-per-producer split). Gates via split-bf16 MFMA (4 terms:
// hi*hi + hi*lo + lo*hi + lo*lo => ~fp32 accuracy). Weights as persistent
// A-fragments in VGPRs. Barrier/ping-pong skeleton identical to R5.
// ---------------------------------------------------------------------------
__global__ void __launch_bounds__(NTHR)
seq2seq_kernel(const float* __restrict__ inputs,
               const float* __restrict__ enc_Wih,
               const float* __restrict__ enc_Whh,
               const float* __restrict__ enc_bih,
               const float* __restrict__ enc_bhh,
               const float* __restrict__ dec_Wih,
               const float* __restrict__ dec_bih,
               const float* __restrict__ dec_bhh,
               const float* __restrict__ lin_W,
               const float* __restrict__ lin_b,
               const float* __restrict__ W2,
               unsigned* __restrict__ hA0,
               unsigned* __restrict__ hB0,
               float* __restrict__ xcor,
               unsigned* __restrict__ bars,
               float* __restrict__ out)
{
    __shared__ unsigned hs[BB * HSW];        // 33 KB packed h tile, padded rows
    __shared__ float gbufA[128 * (BB + 1)];  // gate partials, k-half 0
    __shared__ float gbufB[128 * (BB + 1)];  // gate partials, k-half 1

    const int tid  = threadIdx.x;
    const int w    = tid >> 6;               // wave 0..15
    const int lane = tid & 63;
    const int quad = lane >> 4;              // 0..3
    const int mn   = lane & 15;              // MFMA m/n index (row / batch)
    const int g    = w >> 1;                 // row-group 0..7 (16 rows each)
    const int khalf= w & 1;                  // k in [khalf*256, +256)
    const int bg   = blockIdx.x & (NBG - 1);
    const int lb   = blockIdx.x >> 4;        // hidden-slice owner 0..15
    const int bgbase = bg * BB;

    unsigned* arr = bars + bg * 64;

    // A-fragment rows: local row jl = g*16 + mn  (= gate*32 + hsub encoding)
    const int jl   = g * 16 + mn;
    const int gate = jl >> 5, hsub = jl & 31;
    const size_t wrow = (size_t)(gate * H_ + lb * 32 + hsub) * H_;

    i32x4 Ah[8], Al[8];                      // 64 VGPRs: weight frags hi/lo
    auto loadA = [&](const float* __restrict__ W) {
        const float* rp = W + wrow + khalf * 256 + quad * 8;
        #pragma unroll
        for (int kk = 0; kk < 8; ++kk) {
            float4 f0 = *(const float4*)(rp + kk * 32);
            float4 f1 = *(const float4*)(rp + kk * 32 + 4);
            unsigned b0 = __float_as_uint(f0.x), b1 = __float_as_uint(f0.y);
            unsigned b2 = __float_as_uint(f0.z), b3 = __float_as_uint(f0.w);
            unsigned b4 = __float_as_uint(f1.x), b5 = __float_as_uint(f1.y);
            unsigned b6 = __float_as_uint(f1.z), b7 = __float_as_uint(f1.w);
            i32x4 hi, lo;
            hi.x = __builtin_amdgcn_perm(b1, b0, PERM_HI);
            hi.y = __builtin_amdgcn_perm(b3, b2, PERM_HI);
            hi.z = __builtin_amdgcn_perm(b5, b4, PERM_HI);
            hi.w = __builtin_amdgcn_perm(b7, b6, PERM_HI);
            float r0 = f0.x - __uint_as_float(b0 & 0xffff0000u);
            float r1 = f0.y - __uint_as_float(b1 & 0xffff0000u);
            float r2 = f0.z - __uint_as_float(b2 & 0xffff0000u);
            float r3 = f0.w - __uint_as_float(b3 & 0xffff0000u);
            float r4 = f1.x - __uint_as_float(b4 & 0xffff0000u);
            float r5 = f1.y - __uint_as_float(b5 & 0xffff0000u);
            float r6 = f1.z - __uint_as_float(b6 & 0xffff0000u);
            float r7 = f1.w - __uint_as_float(b7 & 0xffff0000u);
            lo.x = __builtin_amdgcn_perm(__float_as_uint(r1), __float_as_uint(r0), PERM_HI);
            lo.y = __builtin_amdgcn_perm(__float_as_uint(r3), __float_as_uint(r2), PERM_HI);
            lo.z = __builtin_amdgcn_perm(__float_as_uint(r5), __float_as_uint(r4), PERM_HI);
            lo.w = __builtin_amdgcn_perm(__float_as_uint(r7), __float_as_uint(r6), PERM_HI);
            Ah[kk] = hi; Al[kk] = lo;
        }
    };

    // stage bg's packed h (32 KB) global->LDS (agent/sc1 8B loads), padded rows
    auto stage = [&](unsigned* hsrc) {
        unsigned long long* s = (unsigned long long*)hsrc;
        #pragma unroll
        for (int n = 0; n < 4; ++n) {
            unsigned long long v = __hip_atomic_load(s + n * 1024 + tid,
                                       __ATOMIC_RELAXED, __HIP_MEMORY_SCOPE_AGENT);
            int iu  = n * 1024 + tid;            // 8B unit index, 256/row
            int row = iu >> 8, ku = iu & 255;
            *(unsigned long long*)(hs + row * HSW + ku * 2) = v;
        }
    };

    // split-bf16 MFMA: this wave's 16 rows x 16 batches over its 256-k half
    auto dots = [&]() {
        f4v acc = {0.f, 0.f, 0.f, 0.f};
        const unsigned* hr = hs + mn * HSW + khalf * 256 + quad * 8;
        #pragma unroll
        for (int kk = 0; kk < 8; ++kk) {
            uint4 u0 = *(const uint4*)(hr + kk * 32);
            uint4 u1 = *(const uint4*)(hr + kk * 32 + 4);
            i32x4 bh, bl;
            bh.x = __builtin_amdgcn_perm(u0.y, u0.x, PERM_HI);
            bh.y = __builtin_amdgcn_perm(u0.w, u0.z, PERM_HI);
            bh.z = __builtin_amdgcn_perm(u1.y, u1.x, PERM_HI);
            bh.w = __builtin_amdgcn_perm(u1.w, u1.z, PERM_HI);
            bl.x = __builtin_amdgcn_perm(u0.y, u0.x, PERM_LO);
            bl.y = __builtin_amdgcn_perm(u0.w, u0.z, PERM_LO);
            bl.z = __builtin_amdgcn_perm(u1.y, u1.x, PERM_LO);
            bl.w = __builtin_amdgcn_perm(u1.w, u1.z, PERM_LO);
            bf8v ah = __builtin_bit_cast(bf8v, Ah[kk]);
            bf8v al = __builtin_bit_cast(bf8v, Al[kk]);
            bf8v bhv = __builtin_bit_cast(bf8v, bh);
            bf8v blv = __builtin_bit_cast(bf8v, bl);
            acc = __builtin_amdgcn_mfma_f32_16x16x32_bf16(ah, bhv, acc, 0, 0, 0);
            acc = __builtin_amdgcn_mfma_f32_16x16x32_bf16(ah, blv, acc, 0, 0, 0);
            acc = __builtin_amdgcn_mfma_f32_16x16x32_bf16(al, bhv, acc, 0, 0, 0);
            acc = __builtin_amdgcn_mfma_f32_16x16x32_bf16(al, blv, acc, 0, 0, 0);
        }
        // C/D: col=lane&15 (batch), row=quad*4+reg (verified m89/m91)
        float* gb = khalf ? gbufB : gbufA;
        #pragma unroll
        for (int r = 0; r < 4; ++r)
            gb[(g * 16 + quad * 4 + r) * (BB + 1) + mn] = acc[r];
    };

    // h[b=w]·lin_W from packed LDS; result on lane 0 of the wave
    auto proj = [&]() -> float {
        const unsigned* hr = hs + w * HSW;
        uint4 u0 = *(const uint4*)(hr + 4 * lane);
        uint4 u1 = *(const uint4*)(hr + 256 + 4 * lane);
        float4 v0 = *(const float4*)(lin_W + 4 * lane);
        float4 v1 = *(const float4*)(lin_W + 256 + 4 * lane);
        #define RC(u) (__uint_as_float((u) & 0xffff0000u) + __uint_as_float((u) << 16))
        float s = RC(u0.x) * v0.x + RC(u0.y) * v0.y + RC(u0.z) * v0.z + RC(u0.w) * v0.w;
        s = fmaf(RC(u1.x), v1.x, s); s = fmaf(RC(u1.y), v1.y, s);
        s = fmaf(RC(u1.z), v1.z, s); s = fmaf(RC(u1.w), v1.w, s);
        #undef RC
        s += __shfl_down(s, 32); s += __shfl_down(s, 16); s += __shfl_down(s, 8);
        s += __shfl_down(s, 4);  s += __shfl_down(s, 2);  s += __shfl_down(s, 1);
        return s;
    };

    // nonlinearity-state mapping: threads 0..511 own one (hidden,batch) pair
    const int hsubN = tid & 31, bN = tid >> 5;
    const int hidN  = lb * 32 + hsubN;
    const bool stateful = (tid < 512);

    const float ewi = enc_Wih[hidN],          ewf = enc_Wih[H_ + hidN];
    const float ewg = enc_Wih[2 * H_ + hidN], ewo = enc_Wih[3 * H_ + hidN];
    const float ebi = enc_bih[hidN] + enc_bhh[hidN];
    const float ebf = enc_bih[H_ + hidN] + enc_bhh[H_ + hidN];
    const float ebg = enc_bih[2 * H_ + hidN] + enc_bhh[2 * H_ + hidN];
    const float ebo = enc_bih[3 * H_ + hidN] + enc_bhh[3 * H_ + hidN];
    const float linb = lin_b[0];

    loadA(enc_Whh);

    // packed h_0 = 0
    if (stateful)
        __hip_atomic_store(&hA0[(size_t)(bgbase + bN) * H_ + hidN], 0u,
                           __ATOMIC_RELAXED, __HIP_MEMORY_SCOPE_AGENT);

    // producer-side exact bf16 split: h -> [hi16|lo16] word
    auto packh = [](float v) -> unsigned {
        unsigned hb = __float_as_uint(v) & 0xffff0000u;
        float r = v - __uint_as_float(hb);
        return hb | (__float_as_uint(r) >> 16);
    };

    float cc = 0.f;
    unsigned* hcur = hA0;
    unsigned* hnxt = hB0;
    int ph = 0;

    // ---------------- encoder: 1024 steps ----------------
    #pragma unroll 1
    for (int t = 0; t < S_; ++t) {
        bg_barrier(arr, ph++);
        stage(hcur + (size_t)bgbase * H_);
        __syncthreads();
        dots();
        __syncthreads();
        if (stateful) {
            float xv = inputs[(size_t)(bgbase + bN) * S_ + t];
            const int gb = hsubN * (BB + 1) + bN;
            float gi = gbufA[gb]                  + gbufB[gb]                  + fmaf(xv, ewi, ebi);
            float gf = gbufA[gb + 32 * (BB + 1)]  + gbufB[gb + 32 * (BB + 1)]  + fmaf(xv, ewf, ebf);
            float gg = gbufA[gb + 64 * (BB + 1)]  + gbufB[gb + 64 * (BB + 1)]  + fmaf(xv, ewg, ebg);
            float go = gbufA[gb + 96 * (BB + 1)]  + gbufB[gb + 96 * (BB + 1)]  + fmaf(xv, ewo, ebo);
            float i_ = sigmoidf_(gi), f_ = sigmoidf_(gf);
            float g_ = tanhf(gg),     o_ = sigmoidf_(go);
            float cn = fmaf(f_, cc, i_ * g_);
            cc = cn;
            __hip_atomic_store(&hnxt[(size_t)(bgbase + bN) * H_ + hidN],
                               packh(o_ * tanhf(cn)),
                               __ATOMIC_RELAXED, __HIP_MEMORY_SCOPE_AGENT);
        }
        unsigned* tt = hcur; hcur = hnxt; hnxt = tt;
    }

    // ---------------- xcor phase + decoder weight/bias swap ----------------
    bg_barrier(arr, ph++);
    if (lb == 0) {          // xcor[b] = x0_true - (h_enc·lin_W + lin_b)
        stage(hcur + (size_t)bgbase * H_);
        __syncthreads();
        float s = proj();
        if (lane == 0) {
            float x0 = inputs[(size_t)(bgbase + w) * S_ + (S_ - 1)];
            __hip_atomic_store(&xcor[bgbase + w], x0 - (s + linb),
                               __ATOMIC_RELAXED, __HIP_MEMORY_SCOPE_AGENT);
        }
    }
    loadA(W2);
    const float dwi = dec_Wih[hidN],          dwf = dec_Wih[H_ + hidN];
    const float dwg = dec_Wih[2 * H_ + hidN], dwo = dec_Wih[3 * H_ + hidN];
    const float dbi = dec_bih[hidN] + dec_bhh[hidN] + dwi * linb;
    const float dbf = dec_bih[H_ + hidN] + dec_bhh[H_ + hidN] + dwf * linb;
    const float dbg = dec_bih[2 * H_ + hidN] + dec_bhh[2 * H_ + hidN] + dwg * linb;
    const float dbo = dec_bih[3 * H_ + hidN] + dec_bhh[3 * H_ + hidN] + dwo * linb;

    // ---------------- decoder: 256 steps ----------------
    #pragma unroll 1
    for (int t = 0; t < T_; ++t) {
        bg_barrier(arr, ph++);
        stage(hcur + (size_t)bgbase * H_);
        __syncthreads();
        dots();
        if (lb == 0 && t > 0) {       // out[:, t-1] = h_t·lin_W + lin_b
            float s = proj();
            if (lane == 0)
                out[(size_t)(bgbase + w) * T_ + (t - 1)] = s + linb;
        }
        __syncthreads();
        if (stateful) {
            const int gb = hsubN * (BB + 1) + bN;
            float gi = gbufA[gb]                 + gbufB[gb]                 + dbi;
            float gf = gbufA[gb + 32 * (BB + 1)] + gbufB[gb + 32 * (BB + 1)] + dbf;
            float gg = gbufA[gb + 64 * (BB + 1)] + gbufB[gb + 64 * (BB + 1)] + dbg;
            float go = gbufA[gb + 96 * (BB + 1)] + gbufB[gb + 96 * (BB + 1)] + dbo;
            if (t == 0) {
                float xc = __hip_atomic_load(&xcor[bgbase + bN],
                                             __ATOMIC_RELAXED, __HIP_MEMORY_SCOPE_AGENT);
                gi = fmaf(xc, dwi, gi); gf = fmaf(xc, dwf, gf);
                gg = fmaf(xc, dwg, gg); go = fmaf(xc, dwo, go);
            }
            float i_ = sigmoidf_(gi), f_ = sigmoidf_(gf);
            float g_ = tanhf(gg),     o_ = sigmoidf_(go);
            float cn = fmaf(f_, cc, i_ * g_);
            cc = cn;
            __hip_atomic_store(&hnxt[(size_t)(bgbase + bN) * H_ + hidN],
                               packh(o_ * tanhf(cn)),
                               __ATOMIC_RELAXED, __HIP_MEMORY_SCOPE_AGENT);
        }
        unsigned* tt = hcur; hcur = hnxt; hnxt = tt;
    }

    // ---------------- epilogue: out[:, T-1] from h_dec_256 ----------------
    bg_barrier(arr, ph++);
    if (lb == 0) {
        stage(hcur + (size_t)bgbase * H_);
        __syncthreads();
        float s = proj();
        if (lane == 0)
            out[(size_t)(bgbase + w) * T_ + (T_ - 1)] = s + linb;
    }
}

// ---------------------------------------------------------------------------
extern "C" void kernel_launch(void* const* d_in, const int* in_sizes, int n_in,
                              void* d_out, int out_size, void* d_ws, size_t ws_size,
                              hipStream_t stream)
{
    (void)in_sizes; (void)n_in; (void)out_size; (void)ws_size;

    const float* inputs  = (const float*)d_in[0];
    const float* enc_Wih = (const float*)d_in[1];
    const float* enc_Whh = (const float*)d_in[2];
    const float* enc_bih = (const float*)d_in[3];
    const float* enc_bhh = (const float*)d_in[4];
    const float* dec_Wih = (const float*)d_in[5];
    const float* dec_Whh = (const float*)d_in[6];
    const float* dec_bih = (const float*)d_in[7];
    const float* dec_bhh = (const float*)d_in[8];
    const float* lin_W   = (const float*)d_in[9];
    const float* lin_b   = (const float*)d_in[10];
    float* out = (float*)d_out;

    // ws: W2 (4MB) | hA (512KB) | hB (512KB) | xcor (1KB) | barriers (4KB)
    float* W2      = (float*)d_ws;
    unsigned* hA   = (unsigned*)(W2 + (size_t)G4_ * H_);
    unsigned* hB   = hA + (size_t)B_ * H_;
    float* xcor    = (float*)(hB + (size_t)B_ * H_);
    unsigned* bars = (unsigned*)(xcor + B_);

    hipMemsetAsync((void*)bars, 0, NBG * 64 * sizeof(unsigned), stream);

    hipLaunchKernelGGL(fuse_dec_weights, dim3((G4_ * H_) / 256), dim3(256), 0, stream,
                       dec_Whh, dec_Wih, lin_W, W2);

    void* args[] = {
        (void*)&inputs, (void*)&enc_Wih, (void*)&enc_Whh, (void*)&enc_bih, (void*)&enc_bhh,
        (void*)&dec_Wih, (void*)&dec_bih, (void*)&dec_bhh,
        (void*)&lin_W, (void*)&lin_b, (void*)&W2,
        (void*)&hA, (void*)&hB, (void*)&xcor, (void*)&bars, (void*)&out
    };
    hipLaunchCooperativeKernel((void*)seq2seq_kernel, dim3(NBLK), dim3(NTHR),
                               args, 0, stream);
}